// Round 3
// baseline (3093.257 us; speedup 1.0000x reference)
//
#include <hip/hip_runtime.h>

#define T_SEQ 2048
#define HDIM  128
#define GDIM  512
#define BATCH 256

typedef _Float16 f16;
typedef _Float16 f16x2 __attribute__((ext_vector_type(2)));
typedef _Float16 f16x8 __attribute__((ext_vector_type(8)));

#if __has_builtin(__builtin_amdgcn_fdot2)
__device__ __forceinline__ float dot2(f16x2 a, f16x2 b, float c) {
    return __builtin_amdgcn_fdot2(a, b, c, false);
}
#else
__device__ __forceinline__ float dot2(f16x2 a, f16x2 b, float c) {
    return c + (float)a[0] * (float)b[0] + (float)a[1] * (float)b[1];
}
#endif

__device__ __forceinline__ f16x2 mk2(float a, float b) {
    f16x2 r; r[0] = (f16)a; r[1] = (f16)b; return r;
}
// extract half2 pair m (0..3) from an 8-wide f16 vector (free after inlining:
// f16x8 = 4 VGPRs, each VGPR is exactly one f16x2)
__device__ __forceinline__ f16x2 pr(f16x8 v, int m) {
    f16x2 r; r[0] = v[2 * m]; r[1] = v[2 * m + 1]; return r;
}

__device__ __forceinline__ float sigm(float x) {
    return __builtin_amdgcn_rcpf(1.0f + __expf(-x));
}
// tanh(x) = 1 - 2/(e^{2x}+1); exp overflow -> rcp(inf)=0 -> +/-1 saturation is exact
__device__ __forceinline__ float tanh_fast(float x) {
    float e = __expf(2.0f * x);
    return 1.0f - 2.0f * __builtin_amdgcn_rcpf(e + 1.0f);
}

// One block per batch element, 1024 threads (16 waves/CU).
//
// The three 512x128 f16 matvecs per timestep (layer0 recurrence, layer1
// input matvec, layer1 recurrence) are split so EVERY thread owns exactly
// 96 weight halves in registers (96 VGPRs):
//   group A (t < 512, r = t):  wa = W_hh_l0[r, 0:128], wb = W_hh_l1[r, 0:64]
//   group B (t >= 512, r = t-512): wa = W_ih_l1[r, 0:128], wb = W_hh_l1[r, 64:128]
// Both groups index the SAME register arrays (conditionally loaded) so the
// allocator sees 96 weight regs, not 192. g1[r] = g1a[r] (A's partial) +
// g1b[r] (B's partial), summed in the update phase.
//
// Round-2 post-mortem: with plain __launch_bounds__(1024) the backend
// targeted 8 waves/EU -> VGPR_Count=64 -> the 96 weight regs spilled to
// scratch (WRITE_SIZE 155 MB of spill traffic vs 0.5 MB true output).
// Since grid == CU count, only one 16-wave block is ever resident per CU:
// pin exactly 4 waves/EU so the allocator gets the full 128-VGPR budget
// (512-reg file / 4 waves). 96 weights + ~20 working regs fits -> no spill.
__global__
__launch_bounds__(1024, 4)
__attribute__((amdgpu_waves_per_eu(4, 4)))
void lstm_fused(const float* __restrict__ x,
                const float* __restrict__ Wih0,
                const float* __restrict__ Whh0,
                const float* __restrict__ bih0,
                const float* __restrict__ bhh0,
                const float* __restrict__ Wih1,
                const float* __restrict__ Whh1,
                const float* __restrict__ bih1,
                const float* __restrict__ bhh1,
                const float* __restrict__ Wfc,
                const float* __restrict__ bfc,
                float* __restrict__ out)
{
    __shared__ __align__(16) float xs[T_SEQ];       // whole x[b,:] (8 KB)
    __shared__ __align__(16) f16   h0h[HDIM];       // h0 state, f16 (dot input)
    __shared__ __align__(16) f16   h1h[HDIM];       // h1 state, f16
    __shared__ float h0f[HDIM], h1f[HDIM];          // fp32 copies for outputs
    __shared__ float g0[GDIM];                      // layer0 gate preactivations
    __shared__ float g1a[GDIM], g1b[GDIM];          // layer1 partials (A + B)

    const int t  = threadIdx.x;
    const int b  = blockIdx.x;
    const bool gA = (t < 512);
    const int r  = t & 511;

    // stage the full input sequence for this batch element (coalesced)
    if (gA)
        ((float4*)xs)[t] = ((const float4*)(x + (size_t)b * T_SEQ))[t];

    // ---- load per-thread weights into registers (f16-packed, 96 VGPRs) ----
    f16x2 wa[64];  // A: W_hh_l0[r, 0:128] | B: W_ih_l1[r, 0:128]
    f16x2 wb[32];  // A: W_hh_l1[r, 0:64]  | B: W_hh_l1[r, 64:128]
    {
        const float4* pa = (const float4*)((gA ? Whh0 : Wih1) + r * HDIM);
        const float4* pb = (const float4*)(Whh1 + r * HDIM + (gA ? 0 : 64));
#pragma unroll
        for (int c = 0; c < 32; ++c) {
            float4 v = pa[c];
            wa[2 * c]     = mk2(v.x, v.y);
            wa[2 * c + 1] = mk2(v.z, v.w);
        }
#pragma unroll
        for (int c = 0; c < 16; ++c) {
            float4 v = pb[c];
            wb[2 * c]     = mk2(v.x, v.y);
            wb[2 * c + 1] = mk2(v.z, v.w);
        }
    }
    // A: x-weight + layer0 bias | B: no x-term (xw=0), layer1 bias
    const float xw   = gA ? Wih0[r] : 0.f;
    const float bias = gA ? (bih0[r] + bhh0[r]) : (bih1[r] + bhh1[r]);

    if (t < HDIM) {
        h0h[t] = (f16)0.f; h1h[t] = (f16)0.f;
        h0f[t] = 0.f;      h1f[t] = 0.f;
    }
    float c0r = 0.f, c1r = 0.f;  // cell state lives in its update thread
    __syncthreads();

    const f16x8* h0p  = (const f16x8*)h0h;
    // A consumes h1[0:64] (pairs wb = Whh1[:,0:64]); B consumes h1[64:128]
    const f16x8* hsel = ((const f16x8*)h1h) + (gA ? 0 : 8);

    for (int i = 0; i <= T_SEQ; ++i) {
        // ---- compute phase: all 1024 threads, 96 dot2 each, 4 chains ----
        float sa = (i < T_SEQ ? xs[i] : 0.f) * xw + bias;
        float sb = 0.f, sc = 0.f, sd = 0.f;
#pragma unroll
        for (int c = 0; c < 16; ++c) {          // k = 0..127 of h0 (broadcast)
            f16x8 h = h0p[c];
            sa = dot2(wa[4 * c + 0], pr(h, 0), sa);
            sb = dot2(wa[4 * c + 1], pr(h, 1), sb);
            sa = dot2(wa[4 * c + 2], pr(h, 2), sa);
            sb = dot2(wa[4 * c + 3], pr(h, 3), sb);
        }
#pragma unroll
        for (int c = 0; c < 8; ++c) {           // 64 halves of h1 (A: low, B: high)
            f16x8 h = hsel[c];
            sc = dot2(wb[4 * c + 0], pr(h, 0), sc);
            sd = dot2(wb[4 * c + 1], pr(h, 1), sd);
            sc = dot2(wb[4 * c + 2], pr(h, 2), sc);
            sd = dot2(wb[4 * c + 3], pr(h, 3), sd);
        }
        if (gA) {
            g0[r]  = sa + sb;          // full layer0 preactivation
            g1a[r] = sc + sd;          // layer1 recurrence, k = 0..63
        } else {
            g1b[r] = (sa + sb) + (sc + sd);  // layer1 input matvec + k = 64..127
        }
        __syncthreads();

        // ---- update phase: waves 0-1 -> layer0, waves 8-9 -> layer1 ----
        if (t < 128) {
            if (i < T_SEQ) {
                float gi = sigm(g0[t]);
                float gf = sigm(g0[t + 128]);
                float gg = tanh_fast(g0[t + 256]);
                float go = sigm(g0[t + 384]);
                c0r = gf * c0r + gi * gg;
                float h = go * tanh_fast(c0r);
                h0h[t] = (f16)h;
                h0f[t] = h;
            }
        } else if (t >= 512 && t < 640) {
            if (i >= 1) {
                int j = t - 512;
                float gi = sigm(g1a[j]       + g1b[j]);
                float gf = sigm(g1a[j + 128] + g1b[j + 128]);
                float gg = tanh_fast(g1a[j + 256] + g1b[j + 256]);
                float go = sigm(g1a[j + 384] + g1b[j + 384]);
                c1r = gf * c1r + gi * gg;
                float h = go * tanh_fast(c1r);
                h1h[j] = (f16)h;
                h1f[j] = h;
            }
        }
        __syncthreads();
    }

    // ---- outputs: out = [ y(256) | h_n(2*256*128) | c_n(2*256*128) ] ----
    float* hn = out + BATCH;
    float* cn = out + BATCH + 2 * BATCH * HDIM;
    if (t < 128) {
        hn[(size_t)b * HDIM + t] = h0f[t];
        cn[(size_t)b * HDIM + t] = c0r;
    } else if (t >= 512 && t < 640) {
        int j = t - 512;
        hn[BATCH * HDIM + (size_t)b * HDIM + j] = h1f[j];
        cn[BATCH * HDIM + (size_t)b * HDIM + j] = c1r;
    }
    // y[b] = h1_final . W_fc + b_fc  (wave 0 reduction)
    if (t < 64) {
        float p = h1f[t] * Wfc[t] + h1f[t + 64] * Wfc[t + 64];
#pragma unroll
        for (int o = 32; o >= 1; o >>= 1) p += __shfl_down(p, o);
        if (t == 0) out[b] = p + bfc[0];
    }
}

extern "C" void kernel_launch(void* const* d_in, const int* in_sizes, int n_in,
                              void* d_out, int out_size, void* d_ws, size_t ws_size,
                              hipStream_t stream) {
    const float* x    = (const float*)d_in[0];
    const float* Wih0 = (const float*)d_in[1];
    const float* Whh0 = (const float*)d_in[2];
    const float* bih0 = (const float*)d_in[3];
    const float* bhh0 = (const float*)d_in[4];
    const float* Wih1 = (const float*)d_in[5];
    const float* Whh1 = (const float*)d_in[6];
    const float* bih1 = (const float*)d_in[7];
    const float* bhh1 = (const float*)d_in[8];
    const float* Wfc  = (const float*)d_in[9];
    const float* bfc  = (const float*)d_in[10];
    lstm_fused<<<BATCH, 1024, 0, stream>>>(x, Wih0, Whh0, bih0, bhh0,
                                           Wih1, Whh1, bih1, bhh1,
                                           Wfc, bfc, (float*)d_out);
}